// Round 13
// baseline (285.027 us; speedup 1.0000x reference)
//
#include <hip/hip_runtime.h>
#include <hip/hip_bf16.h>

// MultiHeadGraphAttention: n=4096, n_head=8, f_in=1024, f_out=128
// score = s_i + d_j (rank-1); exp(leakyrelu(x)) = max(e^s e^d, e^{.2s} e^{.2d})
// pv: R2 inner structure (split Ed tables, scalar muls, ones-MFMA lsum).
// gemm_hp: grid (8,128), 32-i blocks, wave = 16i x 64o (iw=w>>1, oh=w&1) -> 4 blocks/CU,
//          16 waves/CU (was 8). pack_adj int4+shfl pack. pv_epi 2 idx4/thread. 5 launches.

#define N 4096
#define NH 8
#define FIN 1024
#define FOUT 128

typedef short bf16x8 __attribute__((ext_vector_type(8)));
typedef float f32x4 __attribute__((ext_vector_type(4)));
typedef unsigned int uint;
typedef unsigned short ushort;

__device__ __forceinline__ float b2f(ushort u){ return __uint_as_float(((uint)u)<<16); }
__device__ __forceinline__ uint pk2cvt(float a, float b){
    float2 f; f.x=a; f.y=b;
    __hip_bfloat162 h = __float22bfloat162_rn(f);   // v_cvt_pk_bf16_f32
    uint r; __builtin_memcpy(&r, &h, 4); return r;
}
__device__ __forceinline__ float sane(float x, float lim){ return fminf(fmaxf(x,-lim),lim); }
// XOR-swizzled LDS offset (shorts): row r (0..127), col-group cg (0..7, 8 shorts each).
__device__ __forceinline__ int swz(int r, int cg){ return r*64 + (((cg) ^ (r & 7)) << 3); }
// async global->LDS, 16B per lane. LDS dest = wave-uniform base + lane*16.
__device__ __forceinline__ void glds16(const ushort* g, ushort* l){
    __builtin_amdgcn_global_load_lds(
        (const __attribute__((address_space(1))) void*)g,
        (__attribute__((address_space(3))) void*)l, 16, 0, 0);
}
// mode 0 = float tensors are bf16; mode 1 = fp32
__device__ __forceinline__ int detect_mode(const ushort* hraw){
    ushort u = hraw[2*(threadIdx.x & 63)];
    int e = (u>>7)&0xFF;
    unsigned long long m = __ballot(e>=90 && e<=141);
    return (__popcll(m)>=40)?0:1;
}

// -------------------------------------------------- prep: pack_adj + zero + transpose_w fused
// blocks [0,16384): pack adj (int4/thread, shfl nibble-pack) -> transposed bitmask
// blocks [16384, 16384+nacc+32): zero acc (nacc blocks) + lsum (32 blocks)
// blocks [16384+nacc+32, +256): w -> wT[h][o][f] (bf16)
__global__ __launch_bounds__(256) void prep(
        const int* __restrict__ adj, uint* __restrict__ bitsT,
        float* __restrict__ acc, float* __restrict__ lsum, int nacc,
        const void* __restrict__ wraw, const ushort* __restrict__ hraw,
        ushort* __restrict__ wT) {
    __shared__ ushort tile[64][72];
    int b = blockIdx.x, t = threadIdx.x;
    if (b < 16384) {
        size_t idx = (size_t)b * 1024 + (size_t)t * 4;   // 1024 j-elements per block, one i
        int4 v = *reinterpret_cast<const int4*>(adj + idx);
        int lane = t & 63;
        uint nib = (v.x != 0 ? 1u : 0u) | (v.y != 0 ? 2u : 0u)
                 | (v.z != 0 ? 4u : 0u) | (v.w != 0 ? 8u : 0u);
        uint p1 = __shfl_xor(nib, 1);
        uint by = (lane & 1) ? (p1 | (nib << 4)) : (nib | (p1 << 4));
        uint p2 = __shfl_xor(by, 2);
        uint hf = (lane & 2) ? (p2 | (by << 8)) : (by | (p2 << 8));
        uint p4 = __shfl_xor(hf, 4);
        uint wd = (lane & 4) ? (p4 | (hf << 16)) : (hf | (p4 << 16));
        if ((lane & 7) == 0) {
            uint i  = (uint)(idx >> 12);
            uint jw = ((uint)idx & 4095u) >> 5;
            bitsT[jw * N + i] = wd;
        }
        return;
    }
    int zb = b - 16384;
    if (zb < nacc + 32) {
        float4 z; z.x=0.f; z.y=0.f; z.z=0.f; z.w=0.f;
        if (zb < nacc) reinterpret_cast<float4*>(acc)[(size_t)zb*256+t] = z;
        else           reinterpret_cast<float4*>(lsum)[(size_t)(zb-nacc)*256+t] = z;
        return;
    }
    int bb = zb - (nacc + 32);            // 0..255
    int mode = detect_mode(hraw);
    int f0 = (bb & 15) * 64, o0 = ((bb >> 4) & 1) * 64, h = bb >> 5;
#pragma unroll
    for (int it = 0; it < 2; ++it) {
        int slot = it * 256 + t;
        int row = slot >> 3, c = slot & 7;
        size_t eoff = (size_t)h * (FIN * FOUT) + (size_t)(f0 + row) * FOUT + o0 + c * 8;
        alignas(16) ushort tmp[8];
        if (mode == 0) {
            *reinterpret_cast<uint4*>(tmp) = *reinterpret_cast<const uint4*>((const ushort*)wraw + eoff);
        } else {
            const float* wF = (const float*)wraw;
            float4 x = *reinterpret_cast<const float4*>(wF + eoff);
            float4 y = *reinterpret_cast<const float4*>(wF + eoff + 4);
            uint4 p; p.x = pk2cvt(x.x,x.y); p.y = pk2cvt(x.z,x.w);
            p.z = pk2cvt(y.x,y.y); p.w = pk2cvt(y.z,y.w);
            *reinterpret_cast<uint4*>(tmp) = p;
        }
        *reinterpret_cast<uint4*>(&tile[row][c * 8]) = *reinterpret_cast<uint4*>(tmp);
    }
    __syncthreads();
#pragma unroll
    for (int it = 0; it < 2; ++it) {
        int slot = it * 256 + t;
        int orow = slot >> 3, c = slot & 7;
        alignas(16) ushort tmp[8];
#pragma unroll
        for (int k = 0; k < 8; ++k) tmp[k] = tile[c * 8 + k][orow];
        *reinterpret_cast<uint4*>(wT + (size_t)h * (FIN * FOUT) + (size_t)(o0 + orow) * FIN + f0 + c * 8) =
            *reinterpret_cast<uint4*>(tmp);
    }
}

// -------------------------------------------------- GEMM h' (32i x 128o, BK=64) + s/d dots + exp
// grid dim3(8,128): blockIdx.x = head (XCD = head). 4 blocks/CU, 16 waves/CU.
// Wave w: i-half iw=w>>1 (16 rows), o-half oh=w&1 (64 cols), acc[4].
__global__ __launch_bounds__(256) void gemm_hp(
        const void* __restrict__ hraw, const ushort* __restrict__ wT,
        const void* __restrict__ asraw, const void* __restrict__ adraw,
        ushort* __restrict__ hpT,
        float* __restrict__ es1, float* __restrict__ es2,
        float* __restrict__ ed1, float* __restrict__ ed2) {
    __shared__ ushort Bs[2][FOUT * 64];
    __shared__ float sred[2][32], dred[2][32];
    int mode = detect_mode((const ushort*)hraw);
    int t = threadIdx.x;
    int head = blockIdx.x;
    int i0 = blockIdx.y * 32;
    int w = t >> 6, lane = t & 63, quad = lane >> 4, l16 = lane & 15, wsh = quad * 8;
    int iw = w >> 1, oh = w & 1;
    int arow = i0 + iw * 16 + l16;
    const ushort* hU = (const ushort*)hraw;
    const float*  hF = (const float*)hraw;
    // B staging unchanged: wave w stages rows (w*4+s)*8 + l8 (collectively rows 0..127)
    int l8 = lane >> 3, lk = (lane & 7) ^ (l8 & 7);
    const ushort* gs[4];
#pragma unroll
    for (int s = 0; s < 4; ++s) {
        int o = (w * 4 + s) * 8 + l8;
        gs[s] = wT + (size_t)head * FOUT * FIN + (size_t)o * FIN + lk * 8;
    }

    float asv[4], adv[4];
#pragma unroll
    for (int n = 0; n < 4; ++n) {
        int ai = head * FOUT + (oh * 4 + n) * 16 + l16;
        asv[n] = mode ? ((const float*)asraw)[ai] : b2f(((const ushort*)asraw)[ai]);
        adv[n] = mode ? ((const float*)adraw)[ai] : b2f(((const ushort*)adraw)[ai]);
    }

    f32x4 acc[4] = {};
#pragma unroll
    for (int s = 0; s < 4; ++s) glds16(gs[s], &Bs[0][(w * 4 + s) * 512]);
    uint4 au[2]; float4 af[2][2];
    if (mode == 0) {
#pragma unroll
        for (int kk = 0; kk < 2; ++kk)
            au[kk] = *reinterpret_cast<const uint4*>(hU + (size_t)arow * FIN + kk * 32 + wsh);
    } else {
#pragma unroll
        for (int kk = 0; kk < 2; ++kk) {
            af[kk][0] = *reinterpret_cast<const float4*>(hF + (size_t)arow * FIN + kk * 32 + wsh);
            af[kk][1] = *reinterpret_cast<const float4*>(hF + (size_t)arow * FIN + kk * 32 + wsh + 4);
        }
    }
    __syncthreads();

    for (int c = 0; c < 16; ++c) {
        int k0 = c * 64;
        if (c < 15) {
            ushort* bsw = &Bs[(c + 1) & 1][0];
#pragma unroll
            for (int s = 0; s < 4; ++s)
                glds16(gs[s] + k0 + 64, &bsw[(w * 4 + s) * 512]);
        }
        bf16x8 a2[2];
        if (mode == 0) {
            a2[0] = *reinterpret_cast<bf16x8*>(&au[0]);
            a2[1] = *reinterpret_cast<bf16x8*>(&au[1]);
        } else {
#pragma unroll
            for (int kk = 0; kk < 2; ++kk) {
                uint4 av; av.x = pk2cvt(af[kk][0].x, af[kk][0].y); av.y = pk2cvt(af[kk][0].z, af[kk][0].w);
                av.z = pk2cvt(af[kk][1].x, af[kk][1].y); av.w = pk2cvt(af[kk][1].z, af[kk][1].w);
                a2[kk] = *reinterpret_cast<bf16x8*>(&av);
            }
        }
        if (c < 15) {
            if (mode == 0) {
#pragma unroll
                for (int kk = 0; kk < 2; ++kk)
                    au[kk] = *reinterpret_cast<const uint4*>(hU + (size_t)arow * FIN + k0 + 64 + kk * 32 + wsh);
            } else {
#pragma unroll
                for (int kk = 0; kk < 2; ++kk) {
                    af[kk][0] = *reinterpret_cast<const float4*>(hF + (size_t)arow * FIN + k0 + 64 + kk * 32 + wsh);
                    af[kk][1] = *reinterpret_cast<const float4*>(hF + (size_t)arow * FIN + k0 + 64 + kk * 32 + wsh + 4);
                }
            }
        }
        const ushort* bsr = &Bs[c & 1][0];
#pragma unroll
        for (int kk = 0; kk < 2; ++kk) {
            int cg0 = kk * 4 + quad;
#pragma unroll
            for (int n = 0; n < 4; ++n) {
                int ng = oh * 4 + n;
                bf16x8 b = *reinterpret_cast<const bf16x8*>(&bsr[swz(ng * 16 + l16, cg0)]);
                acc[n] = __builtin_amdgcn_mfma_f32_16x16x32_bf16(a2[kk], b, acc[n], 0, 0, 0);
            }
        }
        if (c < 15) __syncthreads();
    }
#pragma unroll
    for (int n = 0; n < 4; ++n) {
        int ng = oh * 4 + n;
        uint2 pk;
        pk.x = pk2cvt(acc[n][0], acc[n][1]);
        pk.y = pk2cvt(acc[n][2], acc[n][3]);
        *reinterpret_cast<uint2*>(hpT + ((size_t)head * FOUT + ng * 16 + l16) * N + i0 + iw * 16 + quad * 4) = pk;
    }
    // s,d dots: per-o-half partials, combined across halves in the tail
#pragma unroll
    for (int rr = 0; rr < 4; ++rr) {
        float s = 0.f, d = 0.f;
#pragma unroll
        for (int n = 0; n < 4; ++n) { s += acc[n][rr] * asv[n]; d += acc[n][rr] * adv[n]; }
#pragma unroll
        for (int off = 1; off < 16; off <<= 1) { s += __shfl_xor(s, off); d += __shfl_xor(d, off); }
        if (l16 == 0) {
            sred[oh][iw * 16 + quad * 4 + rr] = s;
            dred[oh][iw * 16 + quad * 4 + rr] = d;
        }
    }
    __syncthreads();
    if (t < 32) {
        int i = i0 + t;
        float s = sane(sred[0][t] + sred[1][t], 30.f);
        float d = sane(dred[0][t] + dred[1][t], 30.f);
        es1[head * N + i] = __expf(s);       es2[head * N + i] = __expf(0.2f * s);
        ed1[head * N + i] = __expf(d);       ed2[head * N + i] = __expf(0.2f * d);
    }
}

// -------------------------------------------------- pv: unnormalized P @ h' + fused lsum
// grid (32,8,4) remapped so blocks sharing a (head,kslab) B-panel cluster on one XCD.
__global__ __launch_bounds__(256, 4) void pv_kernel(
        const ushort* __restrict__ hpT,
        const float* __restrict__ es1, const float* __restrict__ es2,
        const float* __restrict__ ed1, const float* __restrict__ ed2,
        const uint* __restrict__ bitsT,
        float* __restrict__ accOut, float* __restrict__ lsum, int use_atomic) {
    __shared__ ushort Bs[2][FOUT * 64];   // 2 x 16 KiB double buffer
    __shared__ float Ed[2][1024];         // exp(d), exp(.2d) for this block's k-range
    int t = threadIdx.x;
    int lin = blockIdx.x + 32 * blockIdx.y + 256 * blockIdx.z;
    int g  = (lin & 7) * 4 + (lin >> 8);   // panel id 0..31
    int ib = (lin >> 3) & 31;              // member 0..31 (i-block)
    int hh = g & 7, kz = g >> 3;
    int i0 = ib * 128, kb = kz * 1024;
    int w = t >> 6, lane = t & 63, quad = lane >> 4, l16 = lane & 15, wsh = quad * 8;
    int irow[2];
    float s1[2], s2[2];
#pragma unroll
    for (int mi = 0; mi < 2; ++mi) {
        irow[mi] = i0 + w * 32 + mi * 16 + l16;
        s1[mi] = es1[hh * N + irow[mi]];
        s2[mi] = es2[hh * N + irow[mi]];
    }
    const uint* bp = bitsT + (size_t)(kb >> 5) * N;
    int l8 = lane >> 3, lk = (lane & 7) ^ (l8 & 7);
    const ushort* gs[4];
#pragma unroll
    for (int s = 0; s < 4; ++s) {
        int o = (w * 4 + s) * 8 + l8;
        gs[s] = hpT + (size_t)hh * FOUT * N + (size_t)o * N + kb + lk * 8;
    }
    bf16x8 ones;
#pragma unroll
    for (int j = 0; j < 8; ++j) ones[j] = (short)0x3F80;   // bf16 1.0

    f32x4 acc[2][8] = {};
    f32x4 accl[2] = {};

    // ---- prologue: stage exp tables, issue B tile 0, load step-0 bits
    float4 ev1 = *reinterpret_cast<const float4*>(ed1 + hh * N + kb + t * 4);
    float4 ev2 = *reinterpret_cast<const float4*>(ed2 + hh * N + kb + t * 4);
    uint bwc[2][2], bwn[2][2];
#pragma unroll
    for (int kk = 0; kk < 2; ++kk)
#pragma unroll
        for (int mi = 0; mi < 2; ++mi) bwc[kk][mi] = bp[(size_t)kk * N + irow[mi]];
#pragma unroll
    for (int s = 0; s < 4; ++s) glds16(gs[s], &Bs[0][(w * 4 + s) * 512]);
    *reinterpret_cast<float4*>(&Ed[0][t * 4]) = ev1;
    *reinterpret_cast<float4*>(&Ed[1][t * 4]) = ev2;
    __syncthreads();

    for (int c = 0; c < 16; ++c) {
        if (c < 15) {
            ushort* bsw = &Bs[(c + 1) & 1][0];
#pragma unroll
            for (int s = 0; s < 4; ++s)
                glds16(gs[s] + (c + 1) * 64, &bsw[(w * 4 + s) * 512]);
#pragma unroll
            for (int kk = 0; kk < 2; ++kk)
#pragma unroll
                for (int mi = 0; mi < 2; ++mi)
                    bwn[kk][mi] = bp[(size_t)((c + 1) * 2 + kk) * N + irow[mi]];
        }
        const ushort* bsr = &Bs[c & 1][0];
#pragma unroll
        for (int kk = 0; kk < 2; ++kk) {
            int kgl = c * 64 + kk * 32 + wsh;
            float4 d1a = *reinterpret_cast<const float4*>(&Ed[0][kgl]);
            float4 d1b = *reinterpret_cast<const float4*>(&Ed[0][kgl + 4]);
            float4 d2a = *reinterpret_cast<const float4*>(&Ed[1][kgl]);
            float4 d2b = *reinterpret_cast<const float4*>(&Ed[1][kgl + 4]);
            bf16x8 am[2];
#pragma unroll
            for (int mi = 0; mi < 2; ++mi) {
                uint word = bwc[kk][mi] >> wsh;
                float e0 = fmaxf(s1[mi]*d1a.x, s2[mi]*d2a.x); e0 = (word & 1u)   ? e0 : 0.f;
                float e1 = fmaxf(s1[mi]*d1a.y, s2[mi]*d2a.y); e1 = (word & 2u)   ? e1 : 0.f;
                float e2 = fmaxf(s1[mi]*d1a.z, s2[mi]*d2a.z); e2 = (word & 4u)   ? e2 : 0.f;
                float e3 = fmaxf(s1[mi]*d1a.w, s2[mi]*d2a.w); e3 = (word & 8u)   ? e3 : 0.f;
                float e4 = fmaxf(s1[mi]*d1b.x, s2[mi]*d2b.x); e4 = (word & 16u)  ? e4 : 0.f;
                float e5 = fmaxf(s1[mi]*d1b.y, s2[mi]*d2b.y); e5 = (word & 32u)  ? e5 : 0.f;
                float e6 = fmaxf(s1[mi]*d1b.z, s2[mi]*d2b.z); e6 = (word & 64u)  ? e6 : 0.f;
                float e7 = fmaxf(s1[mi]*d1b.w, s2[mi]*d2b.w); e7 = (word & 128u) ? e7 : 0.f;
                uint4 av; av.x = pk2cvt(e0, e1); av.y = pk2cvt(e2, e3);
                av.z = pk2cvt(e4, e5); av.w = pk2cvt(e6, e7);
                am[mi] = *reinterpret_cast<bf16x8*>(&av);
                accl[mi] = __builtin_amdgcn_mfma_f32_16x16x32_bf16(am[mi], ones, accl[mi], 0, 0, 0);
            }
            int cg0 = kk * 4 + quad;
            __builtin_amdgcn_s_setprio(1);
#pragma unroll
            for (int n = 0; n < 8; ++n) {
                bf16x8 b = *reinterpret_cast<const bf16x8*>(&bsr[swz(n * 16 + l16, cg0)]);
                acc[0][n] = __builtin_amdgcn_mfma_f32_16x16x32_bf16(am[0], b, acc[0][n], 0, 0, 0);
                acc[1][n] = __builtin_amdgcn_mfma_f32_16x16x32_bf16(am[1], b, acc[1][n], 0, 0, 0);
            }
            __builtin_amdgcn_s_setprio(0);
        }
#pragma unroll
        for (int kk = 0; kk < 2; ++kk)
#pragma unroll
            for (int mi = 0; mi < 2; ++mi) bwc[kk][mi] = bwn[kk][mi];
        if (c < 15) __syncthreads();
    }
    // lsum partials (accl[mi][rr] identical across l16 lanes)
    if (l16 == 0) {
#pragma unroll
        for (int mi = 0; mi < 2; ++mi)
#pragma unroll
            for (int rr = 0; rr < 4; ++rr)
                atomicAdd(&lsum[hh * N + i0 + w * 32 + mi * 16 + quad * 4 + rr], accl[mi][rr]);
    }
    // acc partials: exclusive per-ksplit buffer (plain stores) or atomic fallback
    if (use_atomic) {
#pragma unroll
        for (int mi = 0; mi < 2; ++mi) {
            float* arow = accOut + ((size_t)hh * N + i0 + w * 32 + mi * 16 + quad * 4) * FOUT + l16;
#pragma unroll
            for (int n = 0; n < 8; ++n)
#pragma unroll
                for (int rr = 0; rr < 4; ++rr)
                    atomicAdd(&arow[(size_t)rr * FOUT + n * 16], acc[mi][n][rr]);
        }
    } else {
        float* part = accOut + (size_t)kz * ((size_t)NH * N * FOUT);
#pragma unroll
        for (int mi = 0; mi < 2; ++mi) {
            float* arow = part + ((size_t)hh * N + i0 + w * 32 + mi * 16 + quad * 4) * FOUT + l16;
#pragma unroll
            for (int n = 0; n < 8; ++n)
#pragma unroll
                for (int rr = 0; rr < 4; ++rr)
                    arow[(size_t)rr * FOUT + n * 16] = acc[mi][n][rr];
        }
    }
}

// -------------------------------------------------- pv epilogue: 2 idx4/thread; sum parts +
// inline recip + bias + store; og==0 lanes also write s1r/s2r for weight_kernel.
__global__ __launch_bounds__(256) void pv_epi(
        const float* __restrict__ acc32, const float* __restrict__ lsum,
        const float* __restrict__ es1, const float* __restrict__ es2,
        const void* __restrict__ braw, const ushort* __restrict__ hraw,
        void* __restrict__ outraw,
        float* __restrict__ s1r, float* __restrict__ s2r, int nparts) {
    int mode = detect_mode(hraw);
    const size_t PSTRIDE4 = (size_t)NH * N * FOUT / 4;  // float4 stride per part
#pragma unroll
    for (int pp = 0; pp < 2; ++pp) {
        int idx4 = blockIdx.x * 256 + threadIdx.x + pp * 524288;   // 0 .. 1048575
        int h = idx4 >> 17;
        int i = (idx4 >> 5) & 4095;
        int og = idx4 & 31;
        float4 v = reinterpret_cast<const float4*>(acc32)[idx4];
        if (nparts == 4) {
            float4 a = reinterpret_cast<const float4*>(acc32)[PSTRIDE4 + idx4];
            float4 b = reinterpret_cast<const float4*>(acc32)[2 * PSTRIDE4 + idx4];
            float4 c = reinterpret_cast<const float4*>(acc32)[3 * PSTRIDE4 + idx4];
            v.x += a.x + b.x + c.x; v.y += a.y + b.y + c.y;
            v.z += a.z + b.z + c.z; v.w += a.w + b.w + c.w;
        }
        float lv = lsum[h * N + i];
        float r = (lv > 1e-30f) ? 1.0f / lv : 0.f;
        if (og == 0) {
            s1r[h * N + i] = es1[h * N + i] * r;
            s2r[h * N + i] = es2[h * N + i] * r;
        }
        float4 bv;
        if (mode) bv = reinterpret_cast<const float4*>(braw)[og];
        else {
            const ushort* bu = (const ushort*)braw;
            bv.x = b2f(bu[og*4]); bv.y = b2f(bu[og*4+1]); bv.z = b2f(bu[og*4+2]); bv.w = b2f(bu[og*4+3]);
        }
        v.x = v.x * r + bv.x; v.y = v.y * r + bv.y; v.z = v.z * r + bv.z; v.w = v.w * r + bv.w;
        size_t ob = (size_t)i * (NH * FOUT) + h * FOUT + og * 4;
        if (mode) *reinterpret_cast<float4*>((float*)outraw + ob) = v;
        else {
            uint2 pk; pk.x = pk2cvt(v.x, v.y); pk.y = pk2cvt(v.z, v.w);
            *reinterpret_cast<uint2*>((ushort*)outraw + ob) = pk;
        }
    }
}

// -------------------------------------------------- weight = sum_h attn
__global__ __launch_bounds__(256) void weight_kernel(
        const float* __restrict__ s1r, const float* __restrict__ s2r,
        const float* __restrict__ ed1, const float* __restrict__ ed2,
        const uint* __restrict__ bitsT,
        const ushort* __restrict__ hraw,
        void* __restrict__ outraw) {
    int mode = detect_mode(hraw);
    ushort* woutU = (ushort*)outraw + (size_t)N * (NH * FOUT);
    float*  woutF = (float*)outraw  + (size_t)N * (NH * FOUT);
    int t = threadIdx.x;
    int j = blockIdx.x * 1024 + t * 4;
    int i0 = blockIdx.y * 32;
    float4 d1[NH], d2[NH];
#pragma unroll
    for (int hh = 0; hh < NH; ++hh) {
        d1[hh] = *reinterpret_cast<const float4*>(ed1 + hh * N + j);
        d2[hh] = *reinterpret_cast<const float4*>(ed2 + hh * N + j);
    }
    int wrow = j >> 5;
    int jsh = j & 31;
    for (int i = i0; i < i0 + 32; ++i) {
        uint wbits = bitsT[(size_t)wrow * N + i] >> jsh;
        float sx = 0.f, sy = 0.f, sz = 0.f, sw = 0.f;
#pragma unroll
        for (int hh = 0; hh < NH; ++hh) {
            float a = s1r[hh * N + i];   // block-uniform -> s_load
            float b = s2r[hh * N + i];
            sx += fmaxf(a * d1[hh].x, b * d2[hh].x);
            sy += fmaxf(a * d1[hh].y, b * d2[hh].y);
            sz += fmaxf(a * d1[hh].z, b * d2[hh].z);
            sw += fmaxf(a * d1[hh].w, b * d2[hh].w);
        }
        sx = (wbits & 1u) ? sx : 0.f;
        sy = (wbits & 2u) ? sy : 0.f;
        sz = (wbits & 4u) ? sz : 0.f;
        sw = (wbits & 8u) ? sw : 0.f;
        size_t oidx = (size_t)i * N + j;
        if (mode) {
            float4 st; st.x = sx; st.y = sy; st.z = sz; st.w = sw;
            *reinterpret_cast<float4*>(woutF + oidx) = st;
        } else {
            uint2 pk; pk.x = pk2cvt(sx, sy); pk.y = pk2cvt(sz, sw);
            *reinterpret_cast<uint2*>(woutU + oidx) = pk;
        }
    }
}

// -------------------------------------------------- launch
extern "C" void kernel_launch(void* const* d_in, const int* in_sizes, int n_in,
                              void* d_out, int out_size, void* d_ws, size_t ws_size,
                              hipStream_t stream) {
    (void)in_sizes; (void)n_in; (void)out_size;
    const void* hraw  = d_in[0];                 // [4096][1024]  fp32 (or bf16)
    const int*  adj   = (const int*)d_in[1];     // [4096][4096]  int32
    const void* wraw  = d_in[2];                 // [8][1024][128]
    const void* braw  = d_in[3];                 // [128]
    const void* asraw = d_in[4];                 // [8][128]
    const void* adraw = d_in[5];                 // [8][128]

    char* ws = (char*)d_ws;
    float* lsum = (float*)(ws + 0);
    float* es1  = (float*)(ws + 262144);
    float* es2  = (float*)(ws + 393216);
    float* ed1  = (float*)(ws + 524288);
    float* ed2  = (float*)(ws + 655360);
    float* s1r  = (float*)(ws + 786432);
    float* s2r  = (float*)(ws + 917504);
    uint*  bitsT= (uint*)(ws + 1048576);         // 2 MiB
    ushort* wT  = (ushort*)(ws + 3145728);       // 2 MiB -> small end 5242880

    const size_t SMALL_END = 5242880;
    const size_t PART = 16777216;                // 16 MiB per partial
    float*  acc32; ushort* hpT;
    int use_atomic, nparts;
    if (ws_size >= SMALL_END + 4 * PART + 8388608ull) {
        // partial-store mode: 4 exclusive 16 MiB buffers, no atomics, no acc zeroing
        char* b = ws + SMALL_END;
        acc32 = (float*)b;                       // 64 MiB
        hpT   = (ushort*)(b + 4 * PART);         // 8 MiB
        use_atomic = 0; nparts = 4;
    } else if (ws_size >= SMALL_END + 25165824ull) {
        char* b = ws + SMALL_END;
        acc32 = (float*)b;                       // 16 MiB
        hpT   = (ushort*)(b + PART);             // 8 MiB
        use_atomic = 1; nparts = 1;
    } else {
        char* ob = (char*)d_out;
        acc32 = (float*)(ob + 16777216);         // [16,32) MiB of weight region
        hpT   = (ushort*)(ob + 33554432);        // [32,40) MiB
        use_atomic = 1; nparts = 1;
    }

    int nacc = use_atomic ? 4096 : 0;
    prep<<<16384 + nacc + 32 + 256, 256, 0, stream>>>(adj, bitsT, acc32, lsum, nacc,
                                                      wraw, (const ushort*)hraw, wT);
    gemm_hp<<<dim3(8, 128), 256, 0, stream>>>(hraw, wT, asraw, adraw, hpT,
                                              es1, es2, ed1, ed2);
    pv_kernel<<<dim3(32, 8, 4), 256, 0, stream>>>(hpT, es1, es2, ed1, ed2, bitsT,
                                                  acc32, lsum, use_atomic);
    pv_epi<<<2048, 256, 0, stream>>>(acc32, lsum, es1, es2, braw, (const ushort*)hraw,
                                     d_out, s1r, s2r, nparts);
    weight_kernel<<<dim3(4, 128), 256, 0, stream>>>(s1r, s2r, ed1, ed2, bitsT,
                                                    (const ushort*)hraw, d_out);
}

// Round 14
// 269.397 us; speedup vs baseline: 1.0580x; 1.0580x over previous
//
#include <hip/hip_runtime.h>
#include <hip/hip_bf16.h>

// MultiHeadGraphAttention: n=4096, n_head=8, f_in=1024, f_out=128
// score = s_i + d_j (rank-1); exp(leakyrelu(x)) = max(e^s e^d, e^{.2s} e^{.2d})
// pv: R2 inner structure (split Ed tables, scalar muls, ones-MFMA lsum).
// gemm_hp: R12-exact (8,64) head-major, 64-i blocks (32-i split regressed: 2x staging).
// prep pack: 2x int4/thread. pv_epi: 4 idx4/thread. 5 launches.

#define N 4096
#define NH 8
#define FIN 1024
#define FOUT 128

typedef short bf16x8 __attribute__((ext_vector_type(8)));
typedef float f32x4 __attribute__((ext_vector_type(4)));
typedef unsigned int uint;
typedef unsigned short ushort;

__device__ __forceinline__ float b2f(ushort u){ return __uint_as_float(((uint)u)<<16); }
__device__ __forceinline__ uint pk2cvt(float a, float b){
    float2 f; f.x=a; f.y=b;
    __hip_bfloat162 h = __float22bfloat162_rn(f);   // v_cvt_pk_bf16_f32
    uint r; __builtin_memcpy(&r, &h, 4); return r;
}
__device__ __forceinline__ float sane(float x, float lim){ return fminf(fmaxf(x,-lim),lim); }
// XOR-swizzled LDS offset (shorts): row r (0..127), col-group cg (0..7, 8 shorts each).
__device__ __forceinline__ int swz(int r, int cg){ return r*64 + (((cg) ^ (r & 7)) << 3); }
// async global->LDS, 16B per lane. LDS dest = wave-uniform base + lane*16.
__device__ __forceinline__ void glds16(const ushort* g, ushort* l){
    __builtin_amdgcn_global_load_lds(
        (const __attribute__((address_space(1))) void*)g,
        (__attribute__((address_space(3))) void*)l, 16, 0, 0);
}
// mode 0 = float tensors are bf16; mode 1 = fp32
__device__ __forceinline__ int detect_mode(const ushort* hraw){
    ushort u = hraw[2*(threadIdx.x & 63)];
    int e = (u>>7)&0xFF;
    unsigned long long m = __ballot(e>=90 && e<=141);
    return (__popcll(m)>=40)?0:1;
}
// pack 4 adj ints (one nibble) -> 32-bit word across 8 lanes; returns word, valid on lane%8==0
__device__ __forceinline__ uint packnib(const int4& v, int lane){
    uint nib = (v.x != 0 ? 1u : 0u) | (v.y != 0 ? 2u : 0u)
             | (v.z != 0 ? 4u : 0u) | (v.w != 0 ? 8u : 0u);
    uint p1 = __shfl_xor(nib, 1);
    uint by = (lane & 1) ? (p1 | (nib << 4)) : (nib | (p1 << 4));
    uint p2 = __shfl_xor(by, 2);
    uint hf = (lane & 2) ? (p2 | (by << 8)) : (by | (p2 << 8));
    uint p4 = __shfl_xor(hf, 4);
    return (lane & 4) ? (p4 | (hf << 16)) : (hf | (p4 << 16));
}

// -------------------------------------------------- prep: pack_adj + zero + transpose_w fused
// blocks [0,8192): pack adj (2x int4/thread, shfl nibble-pack) -> transposed bitmask
// blocks [8192, 8192+nacc+32): zero acc (nacc blocks) + lsum (32 blocks)
// blocks [8192+nacc+32, +256): w -> wT[h][o][f] (bf16)
__global__ __launch_bounds__(256) void prep(
        const int* __restrict__ adj, uint* __restrict__ bitsT,
        float* __restrict__ acc, float* __restrict__ lsum, int nacc,
        const void* __restrict__ wraw, const ushort* __restrict__ hraw,
        ushort* __restrict__ wT) {
    __shared__ ushort tile[64][72];
    int b = blockIdx.x, t = threadIdx.x;
    if (b < 8192) {
        int lane = t & 63;
        size_t idxa = (size_t)b * 1024 + (size_t)t * 4;
        size_t idxb = idxa + 8388608;                    // second half of adj
        int4 va = *reinterpret_cast<const int4*>(adj + idxa);
        int4 vb = *reinterpret_cast<const int4*>(adj + idxb);
        uint wda = packnib(va, lane);
        uint wdb = packnib(vb, lane);
        if ((lane & 7) == 0) {
            uint ia  = (uint)(idxa >> 12);
            uint jwa = ((uint)idxa & 4095u) >> 5;
            bitsT[jwa * N + ia] = wda;
            uint ib  = (uint)(idxb >> 12);
            uint jwb = ((uint)idxb & 4095u) >> 5;
            bitsT[jwb * N + ib] = wdb;
        }
        return;
    }
    int zb = b - 8192;
    if (zb < nacc + 32) {
        float4 z; z.x=0.f; z.y=0.f; z.z=0.f; z.w=0.f;
        if (zb < nacc) reinterpret_cast<float4*>(acc)[(size_t)zb*256+t] = z;
        else           reinterpret_cast<float4*>(lsum)[(size_t)(zb-nacc)*256+t] = z;
        return;
    }
    int bb = zb - (nacc + 32);            // 0..255
    int mode = detect_mode(hraw);
    int f0 = (bb & 15) * 64, o0 = ((bb >> 4) & 1) * 64, h = bb >> 5;
#pragma unroll
    for (int it = 0; it < 2; ++it) {
        int slot = it * 256 + t;
        int row = slot >> 3, c = slot & 7;
        size_t eoff = (size_t)h * (FIN * FOUT) + (size_t)(f0 + row) * FOUT + o0 + c * 8;
        alignas(16) ushort tmp[8];
        if (mode == 0) {
            *reinterpret_cast<uint4*>(tmp) = *reinterpret_cast<const uint4*>((const ushort*)wraw + eoff);
        } else {
            const float* wF = (const float*)wraw;
            float4 x = *reinterpret_cast<const float4*>(wF + eoff);
            float4 y = *reinterpret_cast<const float4*>(wF + eoff + 4);
            uint4 p; p.x = pk2cvt(x.x,x.y); p.y = pk2cvt(x.z,x.w);
            p.z = pk2cvt(y.x,y.y); p.w = pk2cvt(y.z,y.w);
            *reinterpret_cast<uint4*>(tmp) = p;
        }
        *reinterpret_cast<uint4*>(&tile[row][c * 8]) = *reinterpret_cast<uint4*>(tmp);
    }
    __syncthreads();
#pragma unroll
    for (int it = 0; it < 2; ++it) {
        int slot = it * 256 + t;
        int orow = slot >> 3, c = slot & 7;
        alignas(16) ushort tmp[8];
#pragma unroll
        for (int k = 0; k < 8; ++k) tmp[k] = tile[c * 8 + k][orow];
        *reinterpret_cast<uint4*>(wT + (size_t)h * (FIN * FOUT) + (size_t)(o0 + orow) * FIN + f0 + c * 8) =
            *reinterpret_cast<uint4*>(tmp);
    }
}

// -------------------------------------------------- GEMM h' (64i x 128o, BK=64) + s/d dots + exp
// grid dim3(8,64): blockIdx.x = head -> XCD = head. (R12-exact)
__global__ __launch_bounds__(256) void gemm_hp(
        const void* __restrict__ hraw, const ushort* __restrict__ wT,
        const void* __restrict__ asraw, const void* __restrict__ adraw,
        ushort* __restrict__ hpT,
        float* __restrict__ es1, float* __restrict__ es2,
        float* __restrict__ ed1, float* __restrict__ ed2) {
    __shared__ ushort Bs[2][FOUT * 64];
    __shared__ float sred[64], dred[64];
    int mode = detect_mode((const ushort*)hraw);
    int t = threadIdx.x;
    int head = blockIdx.x;
    int i0 = blockIdx.y * 64;
    int w = t >> 6, lane = t & 63, quad = lane >> 4, l16 = lane & 15, wsh = quad * 8;
    int arow = i0 + w * 16 + l16;
    const ushort* hU = (const ushort*)hraw;
    const float*  hF = (const float*)hraw;
    int l8 = lane >> 3, lk = (lane & 7) ^ (l8 & 7);
    const ushort* gs[4];
#pragma unroll
    for (int s = 0; s < 4; ++s) {
        int o = (w * 4 + s) * 8 + l8;
        gs[s] = wT + (size_t)head * FOUT * FIN + (size_t)o * FIN + lk * 8;
    }

    float asv[8], adv[8];
#pragma unroll
    for (int n = 0; n < 8; ++n) {
        int ai = head * FOUT + n * 16 + l16;
        asv[n] = mode ? ((const float*)asraw)[ai] : b2f(((const ushort*)asraw)[ai]);
        adv[n] = mode ? ((const float*)adraw)[ai] : b2f(((const ushort*)adraw)[ai]);
    }

    f32x4 acc[8] = {};
#pragma unroll
    for (int s = 0; s < 4; ++s) glds16(gs[s], &Bs[0][(w * 4 + s) * 512]);
    uint4 au[2]; float4 af[2][2];
    if (mode == 0) {
#pragma unroll
        for (int kk = 0; kk < 2; ++kk)
            au[kk] = *reinterpret_cast<const uint4*>(hU + (size_t)arow * FIN + kk * 32 + wsh);
    } else {
#pragma unroll
        for (int kk = 0; kk < 2; ++kk) {
            af[kk][0] = *reinterpret_cast<const float4*>(hF + (size_t)arow * FIN + kk * 32 + wsh);
            af[kk][1] = *reinterpret_cast<const float4*>(hF + (size_t)arow * FIN + kk * 32 + wsh + 4);
        }
    }
    __syncthreads();

    for (int c = 0; c < 16; ++c) {
        int k0 = c * 64;
        if (c < 15) {
            ushort* bsw = &Bs[(c + 1) & 1][0];
#pragma unroll
            for (int s = 0; s < 4; ++s)
                glds16(gs[s] + k0 + 64, &bsw[(w * 4 + s) * 512]);
        }
        bf16x8 a2[2];
        if (mode == 0) {
            a2[0] = *reinterpret_cast<bf16x8*>(&au[0]);
            a2[1] = *reinterpret_cast<bf16x8*>(&au[1]);
        } else {
#pragma unroll
            for (int kk = 0; kk < 2; ++kk) {
                uint4 av; av.x = pk2cvt(af[kk][0].x, af[kk][0].y); av.y = pk2cvt(af[kk][0].z, af[kk][0].w);
                av.z = pk2cvt(af[kk][1].x, af[kk][1].y); av.w = pk2cvt(af[kk][1].z, af[kk][1].w);
                a2[kk] = *reinterpret_cast<bf16x8*>(&av);
            }
        }
        if (c < 15) {
            if (mode == 0) {
#pragma unroll
                for (int kk = 0; kk < 2; ++kk)
                    au[kk] = *reinterpret_cast<const uint4*>(hU + (size_t)arow * FIN + k0 + 64 + kk * 32 + wsh);
            } else {
#pragma unroll
                for (int kk = 0; kk < 2; ++kk) {
                    af[kk][0] = *reinterpret_cast<const float4*>(hF + (size_t)arow * FIN + k0 + 64 + kk * 32 + wsh);
                    af[kk][1] = *reinterpret_cast<const float4*>(hF + (size_t)arow * FIN + k0 + 64 + kk * 32 + wsh + 4);
                }
            }
        }
        const ushort* bsr = &Bs[c & 1][0];
#pragma unroll
        for (int kk = 0; kk < 2; ++kk) {
            int cg0 = kk * 4 + quad;
#pragma unroll
            for (int n = 0; n < 8; ++n) {
                bf16x8 b = *reinterpret_cast<const bf16x8*>(&bsr[swz(n * 16 + l16, cg0)]);
                acc[n] = __builtin_amdgcn_mfma_f32_16x16x32_bf16(a2[kk], b, acc[n], 0, 0, 0);
            }
        }
        if (c < 15) __syncthreads();
    }
#pragma unroll
    for (int n = 0; n < 8; ++n) {
        uint2 pk;
        pk.x = pk2cvt(acc[n][0], acc[n][1]);
        pk.y = pk2cvt(acc[n][2], acc[n][3]);
        *reinterpret_cast<uint2*>(hpT + ((size_t)head * FOUT + n * 16 + l16) * N + i0 + w * 16 + quad * 4) = pk;
    }
#pragma unroll
    for (int rr = 0; rr < 4; ++rr) {
        float s = 0.f, d = 0.f;
#pragma unroll
        for (int n = 0; n < 8; ++n) { s += acc[n][rr] * asv[n]; d += acc[n][rr] * adv[n]; }
#pragma unroll
        for (int off = 1; off < 16; off <<= 1) { s += __shfl_xor(s, off); d += __shfl_xor(d, off); }
        if (l16 == 0) { sred[w * 16 + quad * 4 + rr] = s; dred[w * 16 + quad * 4 + rr] = d; }
    }
    __syncthreads();
    if (t < 64) {
        int i = i0 + t;
        float s = sane(sred[t], 30.f);
        float d = sane(dred[t], 30.f);
        es1[head * N + i] = __expf(s);       es2[head * N + i] = __expf(0.2f * s);
        ed1[head * N + i] = __expf(d);       ed2[head * N + i] = __expf(0.2f * d);
    }
}

// -------------------------------------------------- pv: unnormalized P @ h' + fused lsum
// grid (32,8,4) remapped so blocks sharing a (head,kslab) B-panel cluster on one XCD.
__global__ __launch_bounds__(256, 4) void pv_kernel(
        const ushort* __restrict__ hpT,
        const float* __restrict__ es1, const float* __restrict__ es2,
        const float* __restrict__ ed1, const float* __restrict__ ed2,
        const uint* __restrict__ bitsT,
        float* __restrict__ accOut, float* __restrict__ lsum, int use_atomic) {
    __shared__ ushort Bs[2][FOUT * 64];   // 2 x 16 KiB double buffer
    __shared__ float Ed[2][1024];         // exp(d), exp(.2d) for this block's k-range
    int t = threadIdx.x;
    int lin = blockIdx.x + 32 * blockIdx.y + 256 * blockIdx.z;
    int g  = (lin & 7) * 4 + (lin >> 8);   // panel id 0..31
    int ib = (lin >> 3) & 31;              // member 0..31 (i-block)
    int hh = g & 7, kz = g >> 3;
    int i0 = ib * 128, kb = kz * 1024;
    int w = t >> 6, lane = t & 63, quad = lane >> 4, l16 = lane & 15, wsh = quad * 8;
    int irow[2];
    float s1[2], s2[2];
#pragma unroll
    for (int mi = 0; mi < 2; ++mi) {
        irow[mi] = i0 + w * 32 + mi * 16 + l16;
        s1[mi] = es1[hh * N + irow[mi]];
        s2[mi] = es2[hh * N + irow[mi]];
    }
    const uint* bp = bitsT + (size_t)(kb >> 5) * N;
    int l8 = lane >> 3, lk = (lane & 7) ^ (l8 & 7);
    const ushort* gs[4];
#pragma unroll
    for (int s = 0; s < 4; ++s) {
        int o = (w * 4 + s) * 8 + l8;
        gs[s] = hpT + (size_t)hh * FOUT * N + (size_t)o * N + kb + lk * 8;
    }
    bf16x8 ones;
#pragma unroll
    for (int j = 0; j < 8; ++j) ones[j] = (short)0x3F80;   // bf16 1.0

    f32x4 acc[2][8] = {};
    f32x4 accl[2] = {};

    // ---- prologue: stage exp tables, issue B tile 0, load step-0 bits
    float4 ev1 = *reinterpret_cast<const float4*>(ed1 + hh * N + kb + t * 4);
    float4 ev2 = *reinterpret_cast<const float4*>(ed2 + hh * N + kb + t * 4);
    uint bwc[2][2], bwn[2][2];
#pragma unroll
    for (int kk = 0; kk < 2; ++kk)
#pragma unroll
        for (int mi = 0; mi < 2; ++mi) bwc[kk][mi] = bp[(size_t)kk * N + irow[mi]];
#pragma unroll
    for (int s = 0; s < 4; ++s) glds16(gs[s], &Bs[0][(w * 4 + s) * 512]);
    *reinterpret_cast<float4*>(&Ed[0][t * 4]) = ev1;
    *reinterpret_cast<float4*>(&Ed[1][t * 4]) = ev2;
    __syncthreads();

    for (int c = 0; c < 16; ++c) {
        if (c < 15) {
            ushort* bsw = &Bs[(c + 1) & 1][0];
#pragma unroll
            for (int s = 0; s < 4; ++s)
                glds16(gs[s] + (c + 1) * 64, &bsw[(w * 4 + s) * 512]);
#pragma unroll
            for (int kk = 0; kk < 2; ++kk)
#pragma unroll
                for (int mi = 0; mi < 2; ++mi)
                    bwn[kk][mi] = bp[(size_t)((c + 1) * 2 + kk) * N + irow[mi]];
        }
        const ushort* bsr = &Bs[c & 1][0];
#pragma unroll
        for (int kk = 0; kk < 2; ++kk) {
            int kgl = c * 64 + kk * 32 + wsh;
            float4 d1a = *reinterpret_cast<const float4*>(&Ed[0][kgl]);
            float4 d1b = *reinterpret_cast<const float4*>(&Ed[0][kgl + 4]);
            float4 d2a = *reinterpret_cast<const float4*>(&Ed[1][kgl]);
            float4 d2b = *reinterpret_cast<const float4*>(&Ed[1][kgl + 4]);
            bf16x8 am[2];
#pragma unroll
            for (int mi = 0; mi < 2; ++mi) {
                uint word = bwc[kk][mi] >> wsh;
                float e0 = fmaxf(s1[mi]*d1a.x, s2[mi]*d2a.x); e0 = (word & 1u)   ? e0 : 0.f;
                float e1 = fmaxf(s1[mi]*d1a.y, s2[mi]*d2a.y); e1 = (word & 2u)   ? e1 : 0.f;
                float e2 = fmaxf(s1[mi]*d1a.z, s2[mi]*d2a.z); e2 = (word & 4u)   ? e2 : 0.f;
                float e3 = fmaxf(s1[mi]*d1a.w, s2[mi]*d2a.w); e3 = (word & 8u)   ? e3 : 0.f;
                float e4 = fmaxf(s1[mi]*d1b.x, s2[mi]*d2b.x); e4 = (word & 16u)  ? e4 : 0.f;
                float e5 = fmaxf(s1[mi]*d1b.y, s2[mi]*d2b.y); e5 = (word & 32u)  ? e5 : 0.f;
                float e6 = fmaxf(s1[mi]*d1b.z, s2[mi]*d2b.z); e6 = (word & 64u)  ? e6 : 0.f;
                float e7 = fmaxf(s1[mi]*d1b.w, s2[mi]*d2b.w); e7 = (word & 128u) ? e7 : 0.f;
                uint4 av; av.x = pk2cvt(e0, e1); av.y = pk2cvt(e2, e3);
                av.z = pk2cvt(e4, e5); av.w = pk2cvt(e6, e7);
                am[mi] = *reinterpret_cast<bf16x8*>(&av);
                accl[mi] = __builtin_amdgcn_mfma_f32_16x16x32_bf16(am[mi], ones, accl[mi], 0, 0, 0);
            }
            int cg0 = kk * 4 + quad;
            __builtin_amdgcn_s_setprio(1);
#pragma unroll
            for (int n = 0; n < 8; ++n) {
                bf16x8 b = *reinterpret_cast<const bf16x8*>(&bsr[swz(n * 16 + l16, cg0)]);
                acc[0][n] = __builtin_amdgcn_mfma_f32_16x16x32_bf16(am[0], b, acc[0][n], 0, 0, 0);
                acc[1][n] = __builtin_amdgcn_mfma_f32_16x16x32_bf16(am[1], b, acc[1][n], 0, 0, 0);
            }
            __builtin_amdgcn_s_setprio(0);
        }
#pragma unroll
        for (int kk = 0; kk < 2; ++kk)
#pragma unroll
            for (int mi = 0; mi < 2; ++mi) bwc[kk][mi] = bwn[kk][mi];
        if (c < 15) __syncthreads();
    }
    // lsum partials (accl[mi][rr] identical across l16 lanes)
    if (l16 == 0) {
#pragma unroll
        for (int mi = 0; mi < 2; ++mi)
#pragma unroll
            for (int rr = 0; rr < 4; ++rr)
                atomicAdd(&lsum[hh * N + i0 + w * 32 + mi * 16 + quad * 4 + rr], accl[mi][rr]);
    }
    // acc partials: exclusive per-ksplit buffer (plain stores) or atomic fallback
    if (use_atomic) {
#pragma unroll
        for (int mi = 0; mi < 2; ++mi) {
            float* arow = accOut + ((size_t)hh * N + i0 + w * 32 + mi * 16 + quad * 4) * FOUT + l16;
#pragma unroll
            for (int n = 0; n < 8; ++n)
#pragma unroll
                for (int rr = 0; rr < 4; ++rr)
                    atomicAdd(&arow[(size_t)rr * FOUT + n * 16], acc[mi][n][rr]);
        }
    } else {
        float* part = accOut + (size_t)kz * ((size_t)NH * N * FOUT);
#pragma unroll
        for (int mi = 0; mi < 2; ++mi) {
            float* arow = part + ((size_t)hh * N + i0 + w * 32 + mi * 16 + quad * 4) * FOUT + l16;
#pragma unroll
            for (int n = 0; n < 8; ++n)
#pragma unroll
                for (int rr = 0; rr < 4; ++rr)
                    arow[(size_t)rr * FOUT + n * 16] = acc[mi][n][rr];
        }
    }
}

// -------------------------------------------------- pv epilogue: 4 idx4/thread; sum parts +
// inline recip + bias + store; og==0 lanes also write s1r/s2r for weight_kernel.
__global__ __launch_bounds__(256) void pv_epi(
        const float* __restrict__ acc32, const float* __restrict__ lsum,
        const float* __restrict__ es1, const float* __restrict__ es2,
        const void* __restrict__ braw, const ushort* __restrict__ hraw,
        void* __restrict__ outraw,
        float* __restrict__ s1r, float* __restrict__ s2r, int nparts) {
    int mode = detect_mode(hraw);
    const size_t PSTRIDE4 = (size_t)NH * N * FOUT / 4;  // float4 stride per part
#pragma unroll
    for (int pp = 0; pp < 4; ++pp) {
        int idx4 = blockIdx.x * 256 + threadIdx.x + pp * 262144;   // 0 .. 1048575
        int h = idx4 >> 17;
        int i = (idx4 >> 5) & 4095;
        int og = idx4 & 31;
        float4 v = reinterpret_cast<const float4*>(acc32)[idx4];
        if (nparts == 4) {
            float4 a = reinterpret_cast<const float4*>(acc32)[PSTRIDE4 + idx4];
            float4 b = reinterpret_cast<const float4*>(acc32)[2 * PSTRIDE4 + idx4];
            float4 c = reinterpret_cast<const float4*>(acc32)[3 * PSTRIDE4 + idx4];
            v.x += a.x + b.x + c.x; v.y += a.y + b.y + c.y;
            v.z += a.z + b.z + c.z; v.w += a.w + b.w + c.w;
        }
        float lv = lsum[h * N + i];
        float r = (lv > 1e-30f) ? 1.0f / lv : 0.f;
        if (og == 0) {
            s1r[h * N + i] = es1[h * N + i] * r;
            s2r[h * N + i] = es2[h * N + i] * r;
        }
        float4 bv;
        if (mode) bv = reinterpret_cast<const float4*>(braw)[og];
        else {
            const ushort* bu = (const ushort*)braw;
            bv.x = b2f(bu[og*4]); bv.y = b2f(bu[og*4+1]); bv.z = b2f(bu[og*4+2]); bv.w = b2f(bu[og*4+3]);
        }
        v.x = v.x * r + bv.x; v.y = v.y * r + bv.y; v.z = v.z * r + bv.z; v.w = v.w * r + bv.w;
        size_t ob = (size_t)i * (NH * FOUT) + h * FOUT + og * 4;
        if (mode) *reinterpret_cast<float4*>((float*)outraw + ob) = v;
        else {
            uint2 pk; pk.x = pk2cvt(v.x, v.y); pk.y = pk2cvt(v.z, v.w);
            *reinterpret_cast<uint2*>((ushort*)outraw + ob) = pk;
        }
    }
}

// -------------------------------------------------- weight = sum_h attn
__global__ __launch_bounds__(256) void weight_kernel(
        const float* __restrict__ s1r, const float* __restrict__ s2r,
        const float* __restrict__ ed1, const float* __restrict__ ed2,
        const uint* __restrict__ bitsT,
        const ushort* __restrict__ hraw,
        void* __restrict__ outraw) {
    int mode = detect_mode(hraw);
    ushort* woutU = (ushort*)outraw + (size_t)N * (NH * FOUT);
    float*  woutF = (float*)outraw  + (size_t)N * (NH * FOUT);
    int t = threadIdx.x;
    int j = blockIdx.x * 1024 + t * 4;
    int i0 = blockIdx.y * 32;
    float4 d1[NH], d2[NH];
#pragma unroll
    for (int hh = 0; hh < NH; ++hh) {
        d1[hh] = *reinterpret_cast<const float4*>(ed1 + hh * N + j);
        d2[hh] = *reinterpret_cast<const float4*>(ed2 + hh * N + j);
    }
    int wrow = j >> 5;
    int jsh = j & 31;
    for (int i = i0; i < i0 + 32; ++i) {
        uint wbits = bitsT[(size_t)wrow * N + i] >> jsh;
        float sx = 0.f, sy = 0.f, sz = 0.f, sw = 0.f;
#pragma unroll
        for (int hh = 0; hh < NH; ++hh) {
            float a = s1r[hh * N + i];   // block-uniform -> s_load
            float b = s2r[hh * N + i];
            sx += fmaxf(a * d1[hh].x, b * d2[hh].x);
            sy += fmaxf(a * d1[hh].y, b * d2[hh].y);
            sz += fmaxf(a * d1[hh].z, b * d2[hh].z);
            sw += fmaxf(a * d1[hh].w, b * d2[hh].w);
        }
        sx = (wbits & 1u) ? sx : 0.f;
        sy = (wbits & 2u) ? sy : 0.f;
        sz = (wbits & 4u) ? sz : 0.f;
        sw = (wbits & 8u) ? sw : 0.f;
        size_t oidx = (size_t)i * N + j;
        if (mode) {
            float4 st; st.x = sx; st.y = sy; st.z = sz; st.w = sw;
            *reinterpret_cast<float4*>(woutF + oidx) = st;
        } else {
            uint2 pk; pk.x = pk2cvt(sx, sy); pk.y = pk2cvt(sz, sw);
            *reinterpret_cast<uint2*>(woutU + oidx) = pk;
        }
    }
}

// -------------------------------------------------- launch
extern "C" void kernel_launch(void* const* d_in, const int* in_sizes, int n_in,
                              void* d_out, int out_size, void* d_ws, size_t ws_size,
                              hipStream_t stream) {
    (void)in_sizes; (void)n_in; (void)out_size;
    const void* hraw  = d_in[0];                 // [4096][1024]  fp32 (or bf16)
    const int*  adj   = (const int*)d_in[1];     // [4096][4096]  int32
    const void* wraw  = d_in[2];                 // [8][1024][128]
    const void* braw  = d_in[3];                 // [128]
    const void* asraw = d_in[4];                 // [8][128]
    const void* adraw = d_in[5];                 // [8][128]

    char* ws = (char*)d_ws;
    float* lsum = (float*)(ws + 0);
    float* es1  = (float*)(ws + 262144);
    float* es2  = (float*)(ws + 393216);
    float* ed1  = (float*)(ws + 524288);
    float* ed2  = (float*)(ws + 655360);
    float* s1r  = (float*)(ws + 786432);
    float* s2r  = (float*)(ws + 917504);
    uint*  bitsT= (uint*)(ws + 1048576);         // 2 MiB
    ushort* wT  = (ushort*)(ws + 3145728);       // 2 MiB -> small end 5242880

    const size_t SMALL_END = 5242880;
    const size_t PART = 16777216;                // 16 MiB per partial
    float*  acc32; ushort* hpT;
    int use_atomic, nparts;
    if (ws_size >= SMALL_END + 4 * PART + 8388608ull) {
        // partial-store mode: 4 exclusive 16 MiB buffers, no atomics, no acc zeroing
        char* b = ws + SMALL_END;
        acc32 = (float*)b;                       // 64 MiB
        hpT   = (ushort*)(b + 4 * PART);         // 8 MiB
        use_atomic = 0; nparts = 4;
    } else if (ws_size >= SMALL_END + 25165824ull) {
        char* b = ws + SMALL_END;
        acc32 = (float*)b;                       // 16 MiB
        hpT   = (ushort*)(b + PART);             // 8 MiB
        use_atomic = 1; nparts = 1;
    } else {
        char* ob = (char*)d_out;
        acc32 = (float*)(ob + 16777216);         // [16,32) MiB of weight region
        hpT   = (ushort*)(ob + 33554432);        // [32,40) MiB
        use_atomic = 1; nparts = 1;
    }

    int nacc = use_atomic ? 4096 : 0;
    prep<<<8192 + nacc + 32 + 256, 256, 0, stream>>>(adj, bitsT, acc32, lsum, nacc,
                                                     wraw, (const ushort*)hraw, wT);
    gemm_hp<<<dim3(8, 64), 256, 0, stream>>>(hraw, wT, asraw, adraw, hpT,
                                             es1, es2, ed1, ed2);
    pv_kernel<<<dim3(32, 8, 4), 256, 0, stream>>>(hpT, es1, es2, ed1, ed2, bitsT,
                                                  acc32, lsum, use_atomic);
    pv_epi<<<1024, 256, 0, stream>>>(acc32, lsum, es1, es2, braw, (const ushort*)hraw,
                                     d_out, s1r, s2r, nparts);
    weight_kernel<<<dim3(4, 128), 256, 0, stream>>>(s1r, s2r, ed1, ed2, bitsT,
                                                    (const ushort*)hraw, d_out);
}